// Round 8
// baseline (466.683 us; speedup 1.0000x reference)
//
#include <hip/hip_runtime.h>

// EUNN: 256 layers; each layer = rotation on even pairs (2i,2i+1), then
// rotation on odd pairs (2i+1,2i+2 mod H).
// Pair math: y0 = e^{i*phi} (ct*u - st*v); y1 = st*u + ct*v.
//
// Session ledger:
//  R0: RPW=2 full-row waves, direct L2, compiler schedule. 375us, busy 62%,
//      VGPR 76 (load-use collapsed). Idle ~1400cy/layer/SIMD = exposed L2 lat.
//  R1: C-level reg prefetch -> allocator capped 128, spilled. 902us.
//  R2: LDS DMA staging -> ds_read->use also collapsed + barriers. 424us.
//  R3: bulk prefetch @1 wave/SIMD -> no cover. 436us.
//  R4: PIN4/MEMFENCE -> repack overhead, still collapsed. 452us.
//  R6: wave-sliced half-traffic -> collapsed again (VGPR 124). 427us.
//      Traffic was never the problem; exposed latency is.
//  R7: asm loads + counted vmcnt(8) -> NaN. ROOT CAUSE: next-layer loads in
//      flight ACROSS THE BACKEDGE; A0..A7 are loop-carried -> regalloc phi
//      copies v_mov the in-flight dst (compiler thinks asm outputs complete
//      instantly; SIInsertWaitcnts can't see asm loads) -> copies garbage.
//  R8 (this): same asm-load mechanism, but issue/wait placed so NOTHING is
//      in flight across any block boundary, and only one 8-load group is in
//      flight at a time: issue B at top -> phase A covers it -> vmcnt(0) ->
//      issue next-A -> phase B covers it -> vmcnt(0) -> backedge clean.
//      vmcnt(0) here drains EXACTLY the one landed group == perfect counted
//      wait, immune to count corruption and phi-copy garbage. sched_barrier(0)
//      after each wait per rule #18. Volatile asm = unsinkable loads.

#define H_DIM 1024
#define C2 256
#define RPW 2   // batch rows per wave

typedef float f4 __attribute__((ext_vector_type(4)));

// coef layout: [c][phase][j][lane] as f4 (ct, st, cp, sp), pair i = 8*lane + j
// -> flat f4 index: ((c*2 + phase)*8 + j)*64 + lane,  4 MB total.

__global__ __launch_bounds__(256) void eunn_coef_kernel(
    const float* __restrict__ phi0, const float* __restrict__ theta0,
    const float* __restrict__ phi1, const float* __restrict__ theta1,
    float4* __restrict__ coef) {
    int t = blockIdx.x * 256 + threadIdx.x;     // [0, 262144)
    int i = t & 511;                            // pair index
    int p = (t >> 9) & 1;                       // phase (0: even pairs, 1: odd pairs)
    int c = t >> 10;                            // layer
    const float* phi   = p ? phi1   : phi0;
    const float* theta = p ? theta1 : theta0;
    float ph = phi[i * C2 + c];
    float th = theta[i * C2 + c];
    float sp, cp, st, ct;
    __sincosf(ph, &sp, &cp);
    __sincosf(th, &st, &ct);
    int j = i & 7;
    int l = i >> 3;
    coef[(((c * 2 + p) * 8) + j) * 64 + l] = make_float4(ct, st, cp, sp);
}

__device__ __forceinline__ void rot_pair(const f4 q,
                                         float& ur, float& ui,
                                         float& wr, float& wi) {
    // q = (ct, st, cp, sp)
    float ar = fmaf(-q.y, wr, q.x * ur);   // ct*u - st*v (real part)
    float ai = fmaf(-q.y, wi, q.x * ui);
    float br = fmaf( q.x, wr, q.y * ur);   // st*u + ct*v
    float bi = fmaf( q.x, wi, q.y * ui);
    ur = fmaf(-q.w, ai, q.z * ar);         // e^{i phi} * a
    ui = fmaf( q.w, ar, q.z * ai);
    wr = br;
    wi = bi;
}

// one 16B coef load the compiler cannot see/sink; offset in BYTES (<4096)
#define GLOAD(dst, base, off)                                              \
    asm volatile("global_load_dwordx4 %0, %1, off offset:" #off            \
                 : "=v"(dst) : "v"(base))

// drain all vmem; then wall off code motion so consumers can't hoist above
// the wait (rule #18). At each call site exactly one 8-load group is
// outstanding, so this equals a perfect counted wait with zero over-drain.
#define VMDRAIN                                                            \
    do {                                                                   \
        asm volatile("s_waitcnt vmcnt(0)");                                \
        __builtin_amdgcn_sched_barrier(0);                                 \
    } while (0)

#define ROT2(q, e0, e1)                                                    \
    do {                                                                   \
        _Pragma("unroll")                                                  \
        for (int r = 0; r < RPW; ++r)                                      \
            rot_pair(q, vr[r][e0], vi[r][e0], vr[r][e1], vi[r][e1]);       \
    } while (0)

__global__ __launch_bounds__(256)
__attribute__((amdgpu_waves_per_eu(2, 2)))
void eunn_main_kernel(
    const float* __restrict__ x,
    const f4* __restrict__ coef,
    float* __restrict__ out) {
    const int lane = threadIdx.x & 63;
    const int wave = threadIdx.x >> 6;
    const int row0 = (blockIdx.x * 4 + wave) * RPW;
    const int lnext = (lane + 1) & 63;
    const int lprev = (lane + 63) & 63;

    // lane owns complex elements [16*lane, 16*lane+16) of each of its RPW rows
    float vr[RPW][16], vi[RPW][16];

#pragma unroll
    for (int r = 0; r < RPW; ++r) {
        const f4* src = (const f4*)(x + (size_t)(row0 + r) * (H_DIM * 2)) + lane * 8;
#pragma unroll
        for (int m = 0; m < 8; ++m) {
            f4 f = src[m];
            vr[r][2 * m]     = f.x; vi[r][2 * m]     = f.y;
            vr[r][2 * m + 1] = f.z; vi[r][2 * m + 1] = f.w;
        }
    }

    const f4* cl = coef + lane;   // lane-offset base; + c*1024 + idx*64

    // A0..A7 = phase-A coefs (idx 0..7), B0..B7 = phase-B coefs (idx 8..15).
    f4 A0, A1, A2, A3, A4, A5, A6, A7;
    f4 B0, B1, B2, B3, B4, B5, B6, B7;

    // prologue: load layer 0 phase-A coefs and DRAIN before the loop —
    // nothing may be in flight across the preheader->header edge (phi copies).
    {
        const f4* g0 = cl;           // idx 0..3 at byte offsets 0..3072
        const f4* g1 = cl + 256;     // idx 4..7
        GLOAD(A0, g0, 0); GLOAD(A1, g0, 1024); GLOAD(A2, g0, 2048); GLOAD(A3, g0, 3072);
        GLOAD(A4, g1, 0); GLOAD(A5, g1, 1024); GLOAD(A6, g1, 2048); GLOAD(A7, g1, 3072);
    }
    VMDRAIN;

#pragma unroll 1
    for (int c = 0; c < C2; ++c) {
        const f4* cb = cl + (size_t)c * 1024;
        const f4* cn = cl + (size_t)((c + 1) & (C2 - 1)) * 1024;  // last: wrap (dummy)

        // ---- issue this layer's phase-B loads; phase A compute covers them
        {
            const f4* g2 = cb + 512;   // idx 8..11
            const f4* g3 = cb + 768;   // idx 12..15
            GLOAD(B0, g2, 0); GLOAD(B1, g2, 1024); GLOAD(B2, g2, 2048); GLOAD(B3, g2, 3072);
            GLOAD(B4, g3, 0); GLOAD(B5, g3, 1024); GLOAD(B6, g3, 2048); GLOAD(B7, g3, 3072);
        }

        // ---- phase A: boundary-adjacent pairs first so shuffles issue early
        ROT2(A0, 0, 1);
        ROT2(A7, 14, 15);
        float nbr[RPW], nbi[RPW], pbr[RPW], pbi[RPW];
#pragma unroll
        for (int r = 0; r < RPW; ++r) {
            nbr[r] = __shfl(vr[r][0],  lnext);   // next lane's post-A elem0
            nbi[r] = __shfl(vi[r][0],  lnext);
            pbr[r] = __shfl(vr[r][15], lprev);   // prev lane's post-A elem15
            pbi[r] = __shfl(vi[r][15], lprev);
        }
        ROT2(A1, 2, 3);
        ROT2(A2, 4, 5);
        ROT2(A3, 6, 7);
        ROT2(A4, 8, 9);
        ROT2(A5, 10, 11);
        ROT2(A6, 12, 13);

        VMDRAIN;   // B0..B7 landed (only group outstanding); ~450cy cover

        // boundary coef shuffles (need landed B7; used at phase-B end)
        float qpx = __shfl(B7.x, lprev);   // prev lane's ct'
        float qpy = __shfl(B7.y, lprev);   // prev lane's st'

        // ---- issue next layer's phase-A loads; phase B compute covers them
        {
            const f4* g0 = cn;
            const f4* g1 = cn + 256;
            GLOAD(A0, g0, 0); GLOAD(A1, g0, 1024); GLOAD(A2, g0, 2048); GLOAD(A3, g0, 3072);
            GLOAD(A4, g1, 0); GLOAD(A5, g1, 1024); GLOAD(A6, g1, 2048); GLOAD(A7, g1, 3072);
        }

        // ---- phase B internal pairs (local 2j+1, 2j+2)
        ROT2(B0, 1, 2);
        ROT2(B1, 3, 4);
        ROT2(B2, 5, 6);
        ROT2(B3, 7, 8);
        ROT2(B4, 9, 10);
        ROT2(B5, 11, 12);
        ROT2(B6, 13, 14);

        // phase B boundary pair (my elem15, next lane's elem0)
#pragma unroll
        for (int r = 0; r < RPW; ++r) {
            // new elem15 = e^{i phi}(ct*e15 - st*next_e0)
            float ar = fmaf(-B7.y, nbr[r], B7.x * vr[r][15]);
            float ai = fmaf(-B7.y, nbi[r], B7.x * vi[r][15]);
            vr[r][15] = fmaf(-B7.w, ai, B7.z * ar);
            vi[r][15] = fmaf( B7.w, ar, B7.z * ai);
            // new elem0 = st'*prev_e15 + ct'*e0
            float b0r = fmaf(qpx, vr[r][0], qpy * pbr[r]);
            float b0i = fmaf(qpx, vi[r][0], qpy * pbi[r]);
            vr[r][0] = b0r; vi[r][0] = b0i;
        }

        VMDRAIN;   // next-A landed; nothing in flight across the backedge
    }

#pragma unroll
    for (int r = 0; r < RPW; ++r) {
        f4* dst = (f4*)(out + (size_t)(row0 + r) * (H_DIM * 2)) + lane * 8;
#pragma unroll
        for (int m = 0; m < 8; ++m) {
            f4 o;
            o.x = vr[r][2 * m];     o.y = vi[r][2 * m];
            o.z = vr[r][2 * m + 1]; o.w = vi[r][2 * m + 1];
            dst[m] = o;
        }
    }
}

extern "C" void kernel_launch(void* const* d_in, const int* in_sizes, int n_in,
                              void* d_out, int out_size, void* d_ws, size_t ws_size,
                              hipStream_t stream) {
    const float* x      = (const float*)d_in[0];
    const float* phi0   = (const float*)d_in[1];
    const float* theta0 = (const float*)d_in[2];
    const float* phi1   = (const float*)d_in[3];
    const float* theta1 = (const float*)d_in[4];
    float* out = (float*)d_out;
    float4* coef = (float4*)d_ws;   // 262144 float4 = 4 MB

    // coefficients: 256 layers * 2 phases * 512 pairs = 262144 threads
    hipLaunchKernelGGL(eunn_coef_kernel, dim3(1024), dim3(256), 0, stream,
                       phi0, theta0, phi1, theta1, coef);

    // main: 4096 rows / (4 waves/block * RPW rows/wave) = 512 blocks
    hipLaunchKernelGGL(eunn_main_kernel, dim3(512), dim3(256), 0, stream,
                       x, (const f4*)coef, out);
}